// Round 1
// baseline (2020.325 us; speedup 1.0000x reference)
//
#include <hip/hip_runtime.h>

#define DEVINL __device__ __forceinline__

typedef __attribute__((ext_vector_type(8))) __bf16 bf16x8;
typedef __attribute__((ext_vector_type(4))) float f32x4;
typedef __attribute__((ext_vector_type(8))) unsigned short u16x8;

DEVINL unsigned short f2bf(float x) {
  unsigned u = __builtin_bit_cast(unsigned, x);
  u += 0x7FFFu + ((u >> 16) & 1u);
  return (unsigned short)(u >> 16);
}

#define BARRIER() asm volatile("s_barrier" ::: "memory")

template <int N>
DEVINL void waitvm() {
  asm volatile("s_waitcnt vmcnt(%0)" ::"n"(N) : "memory");
}

DEVINL void gload16(const void* g, void* l) {
  __builtin_amdgcn_global_load_lds(
      (const __attribute__((address_space(1))) void*)g,
      (__attribute__((address_space(3))) void*)l, 16, 0, 0);
}

// ---------------- prep: downsample mean + residual (bf16) ----------------
__global__ __launch_bounds__(256) void prep_kernel(
    const float* __restrict__ F, unsigned short* __restrict__ RES,
    float* __restrict__ DS, int n) {
  const int t = threadIdx.x;
  const int row = blockIdx.x * 16 + (t >> 4);
  const int cg = t & 15;
  if (row >= n) return;
  const float4* f4 = (const float4*)(F + (size_t)row * 128 + cg * 8);
  float4 v0 = f4[0], v1 = f4[1];
  float v[8] = {v0.x, v0.y, v0.z, v0.w, v1.x, v1.y, v1.z, v1.w};
  float s[8] = {v0.x, v0.y, v0.z, v0.w, v1.x, v1.y, v1.z, v1.w};
#pragma unroll
  for (int i = 0; i < 8; ++i) s[i] += __shfl_xor(s[i], 4);
#pragma unroll
  for (int i = 0; i < 8; ++i) s[i] += __shfl_xor(s[i], 8);
  u16x8 rb;
#pragma unroll
  for (int i = 0; i < 8; ++i) rb[i] = f2bf(v[i] - 0.25f * s[i]);
  *(u16x8*)(RES + (size_t)row * 128 + cg * 8) = rb;
  if (cg < 4) {
    float4 d0 = {0.25f * s[0], 0.25f * s[1], 0.25f * s[2], 0.25f * s[3]};
    float4 d1 = {0.25f * s[4], 0.25f * s[5], 0.25f * s[6], 0.25f * s[7]};
    float4* dp = (float4*)(DS + (size_t)row * 32 + cg * 8);
    dp[0] = d0;
    dp[1] = d1;
  }
}

// ---------------- weight pack: B-fragment layout, bf16 ----------------
template <int CIN, int COUT>
DEVINL void pack_one(const float* __restrict__ W, unsigned short* __restrict__ P, int g) {
  const int n = g % COUT;
  const int t = g / COUT;
  const int q = t & 3;
  const int t2 = t >> 2;
  const int ks = t2 % (CIN / 32);
  const int k = t2 / (CIN / 32);
  const float* src = W + ((size_t)k * CIN + ks * 32 + q * 8) * COUT + n;
  unsigned short* dst = P + (size_t)g * 8;
#pragma unroll
  for (int j = 0; j < 8; ++j) dst[j] = f2bf(src[(size_t)j * COUT]);
}

__global__ __launch_bounds__(256) void pack_kernel(
    const float* __restrict__ W0, const float* __restrict__ W1,
    const float* __restrict__ W2, unsigned short* __restrict__ P0,
    unsigned short* __restrict__ P1, unsigned short* __restrict__ P2) {
  int g = blockIdx.x * 256 + threadIdx.x;
  if (g < 55296)
    pack_one<128, 128>(W0, P0, g);
  else if (g < 69120)
    pack_one<128, 32>(W1, P1, g - 55296);
  else if (g < 72576)
    pack_one<32, 32>(W2, P2, g - 69120);
}

// ---------------- zero row N of the gather sources ----------------
__global__ void zero_tail(unsigned short* a, unsigned short* b, unsigned short* c) {
  int t = threadIdx.x;
  if (t < 128) { a[t] = 0; b[t] = 0; }
  if (t < 32) c[t] = 0;
}

// ---------------- SPARSE conv0: 128 -> 128 ----------------
// Voxel density is 14.3% -> 82.5% of gathers hit the zero row. Per (block of
// 256 rows, k): ballot-compact valid rows, MFMA only ceil(valid/32) 32-row
// tiles (pad slots gather the zero row -> contribute 0), scatter-accumulate
// C-fragments into a padded f32 LDS accumulator with ds_add_f32.
// Pipeline: A double-buffered global_load_lds (1 issue/thread/tile), counted
// vmcnt (1 mid-seg, NB+1 at seg boundary where B(k+1) frags are prefetched),
// k-lists built 2 segments ahead from an nbr row preloaded 3 ahead.
// NOTE: row-index packing uses 19 bits (N=300000 < 2^19).
__global__ __launch_bounds__(512, 1) void spconv_sp(
    const unsigned short* __restrict__ X, const unsigned short* __restrict__ Bp,
    const int* __restrict__ nbr, unsigned short* __restrict__ Y, int nr) {
  constexpr int CIN = 128, COUT = 128;
  constexpr int BM = 256, MT = 32;
  constexpr int KS = CIN / 32;    // 4
  constexpr int NF = 2;           // 32-col wave slice (2x4 wave grid on 32x128)
  constexpr int NB = KS * NF;     // 8 B-fragments per lane per k
  constexpr int ACCW = COUT + 4;  // +4 f32 row pad: scatter adds hit distinct banks

  __shared__ float accS[BM * ACCW];           // 135168 B
  __shared__ unsigned short As[2][MT * CIN];  // 16384 B (double-buffered A tile)
  __shared__ int klist[3][BM];                // 3072 B (k, k+1, k+2 lists)
  __shared__ int meta[3];
  __shared__ int wsum[8];

  const int tid = threadIdx.x;
  const int lane = tid & 63;
  const int wave = tid >> 6;
  const int q = lane >> 4;
  const int l16 = lane & 15;
  const int wm = wave >> 2;  // 0..1
  const int wn = wave & 3;   // 0..3
  const int base = blockIdx.x * BM;

  const unsigned short* bbase = Bp + ((size_t)q * COUT + wn * 32 + l16) * 8;

  bf16x8 bf0[NB], bf1[NB];

  auto loadB = [&](bf16x8(&dst)[NB], int k) {
#pragma unroll
    for (int ks = 0; ks < KS; ++ks)
#pragma unroll
      for (int j = 0; j < NF; ++j)
        dst[ks * NF + j] = *(const bf16x8*)(
            bbase + (size_t)k * CIN * COUT + ((size_t)(ks * 4) * COUT + j * 16) * 8);
  };

  auto issueA = [&](int kb, int tt, int bufsel) {
    // 512 threads x 16B = one 32x128 bf16 tile; source pre-swizzled so the
    // linear LDS dest matches the swizzled fragment reads.
    int r = tid >> 4;
    int cc = (tid & 15) << 4;
    int c = (cc ^ ((r & 7) << 4)) >> 4;
    int g = klist[kb][tt * MT + r] & 0x7FFFF;
    gload16(X + (size_t)g * CIN + c * 8, (char*)(&As[bufsel][0]) + tid * 16);
  };

  // compact valid rows of offset k into klist[k%3]; pad to a multiple of MT
  // with zero-row entries; always >= 1 tile so every segment exists.
  auto scanPublish = [&](int k, int v) {
    bool valid = (tid < BM) && (base + tid < nr) && (v != nr);
    unsigned long long b = __ballot(valid);
    if (lane == 0) wsum[wave] = __popcll(b);
    int lanePre = __popcll(b & ((1ull << lane) - 1));
    __syncthreads();
    int pre = lanePre, cnt = 0;
#pragma unroll
    for (int w = 0; w < 4; ++w) {
      int c = wsum[w];
      if (w < wave) pre += c;
      cnt += c;
    }
    int kb = k % 3;
    if (valid) klist[kb][pre] = v | (tid << 19);
    int padded = ((cnt + MT - 1) / MT) * MT;
    if (padded == 0) padded = MT;
    if (tid < padded - cnt) klist[kb][cnt + tid] = nr;  // zero-row pad entries
    if (tid == 0) meta[kb] = padded / MT;
    __syncthreads();
  };

  auto tileCompute = [&](int bufsel, const bf16x8(&bf)[NB], int kb, int tt) {
    const char* Ab = (const char*)(&As[bufsel][0]);
    f32x4 tc[NF] = {};
    const int r = wm * 16 + l16;
#pragma unroll
    for (int ks = 0; ks < KS; ++ks) {
      bf16x8 af = __builtin_bit_cast(
          bf16x8,
          *(const uint4*)(Ab + r * 256 + (((ks * 64 + q * 16) & 255) ^ ((r & 7) << 4))));
#pragma unroll
      for (int j = 0; j < NF; ++j)
        tc[j] = __builtin_amdgcn_mfma_f32_16x16x32_bf16(af, bf[ks * NF + j], tc[j], 0, 0, 0);
    }
    // C layout: col = lane&15, row = q*4 + rr. Scatter rows to orig positions.
#pragma unroll
    for (int rr = 0; rr < 4; ++rr) {
      int o = klist[kb][tt * MT + wm * 16 + q * 4 + rr] >> 19;
      float* ap = &accS[o * ACCW + wn * 32 + l16];
#pragma unroll
      for (int j = 0; j < NF; ++j) atomicAdd(ap + j * 16, tc[j][rr]);
    }
  };

  // ---- prologue ----
  for (int i = tid; i < BM * ACCW; i += 512) accS[i] = 0.f;
  {
    int v0 = nr;
    if (tid < BM && base + tid < nr) v0 = nbr[base + tid];
    scanPublish(0, v0);
    int v1 = nr;
    if (tid < BM && base + tid < nr) v1 = nbr[(size_t)nr + base + tid];
    scanPublish(1, v1);
  }
  int vPre = nr;
  if (tid < BM && base + tid < nr) vPre = nbr[(size_t)2 * nr + base + tid];

  loadB(bf0, 0);
  issueA(0, 0, 0);
  int bp = 0;

#pragma unroll 1
  for (int k = 0; k < 27; ++k) {
    const int kb = k % 3;
    const int T = meta[kb];
#pragma unroll 1
    for (int tt = 0; tt < T; ++tt) {
      const bool lastT = (tt == T - 1);
      if (!lastT) {
        issueA(kb, tt + 1, bp ^ 1);
        waitvm<1>();  // keep only the just-issued A tile in flight
      } else if (k < 26) {
        issueA((k + 1) % 3, 0, bp ^ 1);
        if (k & 1) loadB(bf0, k + 1);
        else loadB(bf1, k + 1);
        waitvm<NB + 1>();  // keep next A tile + B(k+1) frags in flight
      } else {
        waitvm<0>();
      }
      BARRIER();
      if (k & 1) tileCompute(bp, bf1, kb, tt);
      else tileCompute(bp, bf0, kb, tt);
      if (tt == 0 && k + 2 < 27) {
        scanPublish(k + 2, vPre);  // list built 2 segments ahead
        if (k + 3 < 27) {
          vPre = nr;
          if (tid < BM && base + tid < nr)
            vPre = nbr[(size_t)(k + 3) * nr + base + tid];
        }
      }
      BARRIER();
      bp ^= 1;
    }
  }

  // ---- epilogue: f32 accumulator -> bf16 rows ----
  __syncthreads();
  for (int s = tid; s < BM * (COUT / 8); s += 512) {
    int rrow = s >> 4, c8 = (s & 15) << 3;
    int row = base + rrow;
    if (row < nr) {
      const float* ap = &accS[rrow * ACCW + c8];
      u16x8 ob;
#pragma unroll
      for (int i = 0; i < 8; ++i) ob[i] = f2bf(ap[i]);
      *(u16x8*)(Y + (size_t)row * COUT + c8) = ob;
    }
  }
}

// ---------------- dense gather-GEMM sparse conv (conv1 / conv2) ----------------
template <int CIN, int COUT, int WM, int WN, bool FINAL, int MINB>
__global__ __launch_bounds__(256, MINB) void spconv(
    const unsigned short* __restrict__ X, const unsigned short* __restrict__ Bp,
    const int* __restrict__ nbr, unsigned short* __restrict__ Y,
    float* __restrict__ OUT, const float* __restrict__ DS, int nr) {
  constexpr int BM = 128;
  constexpr int KS = CIN / 32;
  constexpr int WROWS = BM / WM;
  constexpr int WCOLS = COUT / WN;
  constexpr int MF = WROWS / 16;
  constexpr int NF = WCOLS / 16;
  constexpr int CPR = CIN / 8;
  constexpr int SWZ = (CPR < 8 ? CPR - 1 : 7);
  constexpr int ROWB = CIN * 2;
  constexpr int ACH = BM * CPR;
  constexpr int APF = ACH / 256;
  constexpr int NB = KS * NF;

  __shared__ unsigned short As[2][BM * CIN];
  __shared__ int IdxS[27 * BM];

  const int tid = threadIdx.x;
  const int lane = tid & 63;
  const int wave = tid >> 6;
  const int wm = wave / WN;
  const int wn = wave % WN;
  const int base = blockIdx.x * BM;
  const int q = lane >> 4;
  const int l16 = lane & 15;

  for (int f = tid; f < 27 * BM; f += 256) {
    int nn = base + (f & (BM - 1));
    IdxS[f] = (nn < nr) ? nbr[(size_t)(f >> 7) * nr + nn] : nr;
  }
  __syncthreads();

  const unsigned short* bbase = Bp + ((size_t)q * COUT + wn * WCOLS + l16) * 8;

  bf16x8 bA[NB], bB[NB];

  auto loadB = [&](bf16x8(&dst)[NB], int k) {
#pragma unroll
    for (int ks = 0; ks < KS; ++ks)
#pragma unroll
      for (int j = 0; j < NF; ++j)
        dst[ks * NF + j] = *(const bf16x8*)(
            bbase + ((size_t)k * CIN * COUT) + ((size_t)(ks * 4) * COUT + j * 16) * 8);
  };

  auto issueA = [&](int k) {
    const int kb = k & 1;
#pragma unroll
    for (int pp = 0; pp < APF; ++pp) {
      int slot = pp * 256 + tid;
      int r = slot / CPR;
      int cc = (slot % CPR) * 16;
      int c = (cc ^ ((r & SWZ) << 4)) >> 4;
      int g = IdxS[k * BM + r];
      gload16(X + (size_t)g * CIN + c * 8, (char*)(&As[kb][0]) + slot * 16);
    }
  };

  f32x4 acc[MF][NF] = {};

  auto mfmaStep = [&](int kb, const bf16x8(&bf)[NB]) {
    const char* Ab = (const char*)(&As[kb][0]);
#pragma unroll
    for (int ks = 0; ks < KS; ++ks) {
      bf16x8 af[MF];
#pragma unroll
      for (int i = 0; i < MF; ++i) {
        int r = wm * WROWS + i * 16 + l16;
        int db = r * ROWB + (((ks * 64 + q * 16) & (ROWB - 1)) ^ ((r & SWZ) << 4));
        af[i] = __builtin_bit_cast(bf16x8, *(const uint4*)(Ab + db));
      }
#pragma unroll
      for (int i = 0; i < MF; ++i)
#pragma unroll
        for (int j = 0; j < NF; ++j)
          acc[i][j] = __builtin_amdgcn_mfma_f32_16x16x32_bf16(af[i], bf[ks * NF + j],
                                                              acc[i][j], 0, 0, 0);
    }
  };

  loadB(bA, 0);
  issueA(0);

#pragma unroll 1
  for (int k = 0; k < 26; k += 2) {
    loadB(bB, k + 1);
    issueA(k + 1);
    waitvm<NB + APF>();
    BARRIER();
    mfmaStep(0, bA);
    BARRIER();
    if (k + 2 < 27) {
      loadB(bA, k + 2);
      issueA(k + 2);
      waitvm<NB + APF>();
    } else {
      waitvm<0>();
    }
    BARRIER();
    mfmaStep(1, bB);
    BARRIER();
  }
  waitvm<0>();
  BARRIER();
  mfmaStep(0, bA);

#pragma unroll
  for (int i = 0; i < MF; ++i)
#pragma unroll
    for (int j = 0; j < NF; ++j)
#pragma unroll
      for (int r = 0; r < 4; ++r) {
        int row = base + wm * WROWS + i * 16 + q * 4 + r;
        int col = wn * WCOLS + j * 16 + l16;
        if (row < nr) {
          float v = acc[i][j][r];
          if constexpr (FINAL)
            OUT[(size_t)row * COUT + col] = v + DS[(size_t)row * COUT + col];
          else
            Y[(size_t)row * COUT + col] = f2bf(v);
        }
      }
}

// ---------------- launch ----------------
extern "C" void kernel_launch(void* const* d_in, const int* in_sizes, int n_in,
                              void* d_out, int out_size, void* d_ws, size_t ws_size,
                              hipStream_t stream) {
  const float* feats = (const float*)d_in[0];
  const float* W0 = (const float*)d_in[1];
  const float* W1 = (const float*)d_in[2];
  const float* W2 = (const float*)d_in[3];
  const int* nbr = (const int*)d_in[4];
  const int n = in_sizes[0] / 128;
  float* out = (float*)d_out;

  char* p = (char*)d_ws;
  auto take = [&](size_t bytes) {
    char* r = p;
    p += (bytes + 255) & ~(size_t)255;
    return r;
  };
  unsigned short* resB = (unsigned short*)take((size_t)(n + 1) * 128 * 2);
  unsigned short* y0 = (unsigned short*)take((size_t)(n + 1) * 128 * 2);
  unsigned short* y1 = (unsigned short*)take((size_t)(n + 1) * 32 * 2);
  float* ds = (float*)take((size_t)n * 32 * 4);
  unsigned short* p0 = (unsigned short*)take((size_t)27 * 128 * 128 * 2);
  unsigned short* p1 = (unsigned short*)take((size_t)27 * 128 * 32 * 2);
  unsigned short* p2 = (unsigned short*)take((size_t)27 * 32 * 32 * 2);

  prep_kernel<<<(n + 15) / 16, 256, 0, stream>>>(feats, resB, ds, n);
  pack_kernel<<<284, 256, 0, stream>>>(W0, W1, W2, p0, p1, p2);
  zero_tail<<<1, 128, 0, stream>>>(resB + (size_t)n * 128, y0 + (size_t)n * 128,
                                   y1 + (size_t)n * 32);
  // conv0: 128->128, sparsity-aware (valid-row compaction + LDS f32 scatter acc)
  const int gb0 = (n + 255) / 256;
  spconv_sp<<<gb0, 512, 0, stream>>>(resB, p0, nbr, y0, n);
  const int gb = (n + 127) / 128;
  // conv1: 128->32 dense path. WM=4,WN=1 -> NF=2, NB=8.
  spconv<128, 32, 4, 1, false, 2>
      <<<gb, 256, 0, stream>>>(y0, p1, nbr, y1, nullptr, nullptr, n);
  // conv2: 32->32 dense path. KS=1, NB=2, small LDS -> 4+ blocks/CU.
  spconv<32, 32, 4, 1, true, 4>
      <<<gb, 256, 0, stream>>>(y1, p2, nbr, nullptr, out, ds, n);
}

// Round 2
// 728.305 us; speedup vs baseline: 2.7740x; 2.7740x over previous
//
#include <hip/hip_runtime.h>

#define DEVINL __device__ __forceinline__

typedef __attribute__((ext_vector_type(8))) __bf16 bf16x8;
typedef __attribute__((ext_vector_type(4))) float f32x4;
typedef __attribute__((ext_vector_type(8))) unsigned short u16x8;

DEVINL unsigned short f2bf(float x) {
  unsigned u = __builtin_bit_cast(unsigned, x);
  u += 0x7FFFu + ((u >> 16) & 1u);
  return (unsigned short)(u >> 16);
}

#define BARRIER() asm volatile("s_barrier" ::: "memory")

template <int N>
DEVINL void waitvm() {
  asm volatile("s_waitcnt vmcnt(%0)" ::"n"(N) : "memory");
}

DEVINL void gload16(const void* g, void* l) {
  __builtin_amdgcn_global_load_lds(
      (const __attribute__((address_space(1))) void*)g,
      (__attribute__((address_space(3))) void*)l, 16, 0, 0);
}

// ---------------- prep: downsample mean + residual (bf16) ----------------
__global__ __launch_bounds__(256) void prep_kernel(
    const float* __restrict__ F, unsigned short* __restrict__ RES,
    float* __restrict__ DS, int n) {
  const int t = threadIdx.x;
  const int row = blockIdx.x * 16 + (t >> 4);
  const int cg = t & 15;
  if (row >= n) return;
  const float4* f4 = (const float4*)(F + (size_t)row * 128 + cg * 8);
  float4 v0 = f4[0], v1 = f4[1];
  float v[8] = {v0.x, v0.y, v0.z, v0.w, v1.x, v1.y, v1.z, v1.w};
  float s[8] = {v0.x, v0.y, v0.z, v0.w, v1.x, v1.y, v1.z, v1.w};
#pragma unroll
  for (int i = 0; i < 8; ++i) s[i] += __shfl_xor(s[i], 4);
#pragma unroll
  for (int i = 0; i < 8; ++i) s[i] += __shfl_xor(s[i], 8);
  u16x8 rb;
#pragma unroll
  for (int i = 0; i < 8; ++i) rb[i] = f2bf(v[i] - 0.25f * s[i]);
  *(u16x8*)(RES + (size_t)row * 128 + cg * 8) = rb;
  if (cg < 4) {
    float4 d0 = {0.25f * s[0], 0.25f * s[1], 0.25f * s[2], 0.25f * s[3]};
    float4 d1 = {0.25f * s[4], 0.25f * s[5], 0.25f * s[6], 0.25f * s[7]};
    float4* dp = (float4*)(DS + (size_t)row * 32 + cg * 8);
    dp[0] = d0;
    dp[1] = d1;
  }
}

// ---------------- weight pack: B-fragment layout, bf16 ----------------
template <int CIN, int COUT>
DEVINL void pack_one(const float* __restrict__ W, unsigned short* __restrict__ P, int g) {
  const int n = g % COUT;
  const int t = g / COUT;
  const int q = t & 3;
  const int t2 = t >> 2;
  const int ks = t2 % (CIN / 32);
  const int k = t2 / (CIN / 32);
  const float* src = W + ((size_t)k * CIN + ks * 32 + q * 8) * COUT + n;
  unsigned short* dst = P + (size_t)g * 8;
#pragma unroll
  for (int j = 0; j < 8; ++j) dst[j] = f2bf(src[(size_t)j * COUT]);
}

__global__ __launch_bounds__(256) void pack_kernel(
    const float* __restrict__ W0, const float* __restrict__ W1,
    const float* __restrict__ W2, unsigned short* __restrict__ P0,
    unsigned short* __restrict__ P1, unsigned short* __restrict__ P2) {
  int g = blockIdx.x * 256 + threadIdx.x;
  if (g < 55296)
    pack_one<128, 128>(W0, P0, g);
  else if (g < 69120)
    pack_one<128, 32>(W1, P1, g - 55296);
  else if (g < 72576)
    pack_one<32, 32>(W2, P2, g - 69120);
}

// ---------------- zero row N of the gather sources ----------------
__global__ void zero_tail(unsigned short* a, unsigned short* b, unsigned short* c) {
  int t = threadIdx.x;
  if (t < 128) { a[t] = 0; b[t] = 0; }
  if (t < 32) c[t] = 0;
}

// ---------------- SPARSE conv0 v2: 128 -> 128 ----------------
// All tile descriptors built ONCE in the prologue (27 ballots); main loop is a
// flat uniform tile stream: 4-buffer A (global_load_lds issued 2 tiles ahead),
// B frags 1 tile ahead, one counted waitvm<10> + one barrier per tile, plain
// (non-atomic) LDS f32 read-add-write scatter (race-free: rows unique within a
// compacted tile, cols partitioned by wave, tiles barrier-separated), dummy
// flush tiles for a branch-free tail. Pad gathers hit zero row nr; pad dests
// hit dummy acc row BM.
__global__ __launch_bounds__(512, 1) void spconv_sp(
    const unsigned short* __restrict__ X, const unsigned short* __restrict__ Bp,
    const int* __restrict__ nbr, unsigned short* __restrict__ Y, int nr) {
  constexpr int CIN = 128, COUT = 128;
  constexpr int BM = 192, MT = 32;
  constexpr int KS = CIN / 32;   // 4
  constexpr int NF = 2;          // wave grid 2x4 over 32x128 tile
  constexpr int NB = KS * NF;    // 8 B-frags per lane per tile
  constexpr int ACCW = COUT + 4; // padded accumulator row
  constexpr int NROWS = BM + 1;  // + dummy row for pad entries
  constexpr int MAXT = 27 * 6 + 4;

  __shared__ float accS[NROWS * ACCW];        // 101,904 B
  __shared__ unsigned short As[4][MT * CIN];  //  32,768 B
  __shared__ int klist[MAXT * MT];            //  21,248 B
  __shared__ int tileK[MAXT + 2];
  __shared__ int wsum[8];

  const int tid = threadIdx.x;
  const int lane = tid & 63;
  const int wave = tid >> 6;
  const int q = lane >> 4;
  const int l16 = lane & 15;
  const int wm = wave >> 2;  // 0..1: 16-row half of tile
  const int wn = wave & 3;   // 0..3: 32-col slice
  const int base = blockIdx.x * BM;

  // ---- zero accumulator ----
  for (int i = tid; i < NROWS * ACCW; i += 512) accS[i] = 0.f;

  // ---- build compacted tile lists for all 27 offsets ----
  const bool rowOk = (tid < BM) && (base + tid < nr);
  int nt = 0;
  int vNext = nr;
  if (rowOk) vNext = nbr[base + tid];
#pragma unroll 1
  for (int k = 0; k < 27; ++k) {
    int v = vNext;
    if (k + 1 < 27) {
      vNext = nr;
      if (rowOk) vNext = nbr[(size_t)(k + 1) * nr + base + tid];
    }
    bool valid = rowOk && (v != nr);
    unsigned long long b = __ballot(valid);
    if (lane == 0) wsum[wave] = __popcll(b);
    int lanePre = __popcll(b & ((1ull << lane) - 1));
    __syncthreads();
    int pre = lanePre, cnt = 0;
#pragma unroll
    for (int w = 0; w < 3; ++w) {
      int c = wsum[w];
      if (w < wave) pre += c;
      cnt += c;
    }
    if (cnt) {
      int tiles = (cnt + MT - 1) >> 5;
      if (valid) klist[nt * MT + pre] = v | (tid << 19);
      int pad = tiles * MT - cnt;
      if (tid < pad) klist[nt * MT + cnt + tid] = nr | (BM << 19);
      if (tid < tiles) tileK[nt + tid] = k;
      nt += tiles;
    }
    __syncthreads();
  }
  // dummy flush tiles (4 issued, 2 computed) — keeps the loop branch-free
  if (tid < 4 * MT) klist[nt * MT + tid] = nr | (BM << 19);
  if (tid < 6) tileK[nt + tid] = 0;
  __syncthreads();
  const int NT = nt + 2;

  // ---- per-lane B base (frag layout identical to pack_kernel) ----
  const unsigned short* bbase = Bp + ((size_t)q * COUT + wn * 32 + l16) * 8;

  bf16x8 bfE[NB], bfO[NB];

  auto loadB = [&](bf16x8(&dst)[NB], int k) {
#pragma unroll
    for (int ks = 0; ks < KS; ++ks)
#pragma unroll
      for (int j = 0; j < NF; ++j)
        dst[ks * NF + j] = *(const bf16x8*)(
            bbase + (size_t)k * CIN * COUT + ((size_t)(ks * 4) * COUT + j * 16) * 8);
  };

  auto issueA = [&](int t) {
    int r = tid >> 4;
    int cc = (tid & 15) << 4;
    int c = (cc ^ ((r & 7) << 4)) >> 4;  // pre-swizzled source chunk
    int g = klist[t * MT + r] & 0x7FFFF;
    gload16(X + (size_t)g * CIN + c * 8, (char*)(&As[t & 3][0]) + tid * 16);
  };

  auto compute = [&](int t, const bf16x8(&bf)[NB]) {
    const char* Ab = (const char*)(&As[t & 3][0]);
    int4 e = *(const int4*)&klist[t * MT + wm * 16 + q * 4];
    f32x4 tc[NF] = {};
    const int row = wm * 16 + l16;
#pragma unroll
    for (int ks = 0; ks < KS; ++ks) {
      bf16x8 af = __builtin_bit_cast(
          bf16x8,
          *(const uint4*)(Ab + row * 256 + (((ks * 64 + q * 16) & 255) ^ ((row & 7) << 4))));
#pragma unroll
      for (int j = 0; j < NF; ++j)
        tc[j] = __builtin_amdgcn_mfma_f32_16x16x32_bf16(af, bf[ks * NF + j], tc[j], 0, 0, 0);
    }
    int d[4] = {e.x >> 19, e.y >> 19, e.z >> 19, e.w >> 19};
#pragma unroll
    for (int rr = 0; rr < 4; ++rr) {
      int idx = d[rr] * ACCW + wn * 32 + l16;
      accS[idx] += tc[0][rr];
      accS[idx + 16] += tc[1][rr];
    }
  };

  // ---- prime: A(0), B(0), A(1) in flight ----
  issueA(0);
  loadB(bfE, tileK[0]);
  issueA(1);
  int kB = tileK[1];

  // ---- flat tile stream ----
#pragma unroll 1
  for (int t = 0; t < NT; ++t) {
    if (!(t & 1)) loadB(bfO, kB);  // B(t+1)
    else          loadB(bfE, kB);
    issueA(t + 2);                 // A(t+2) into buffer (t+2)&3
    kB = tileK[t + 2];
    waitvm<10>();                  // A(t),B(t) landed; A(t+1),B(t+1),A(t+2) in flight
    BARRIER();
    if (!(t & 1)) compute(t, bfE);
    else          compute(t, bfO);
    asm volatile("s_waitcnt lgkmcnt(0)" ::: "memory");  // acc RMW visible
    BARRIER();
  }

  // ---- epilogue: f32 accumulator -> bf16 rows ----
  __syncthreads();
  for (int s = tid; s < BM * (COUT / 8); s += 512) {
    int rrow = s >> 4, c8 = (s & 15) << 3;
    int row = base + rrow;
    if (row < nr) {
      const float* ap = &accS[rrow * ACCW + c8];
      u16x8 ob;
#pragma unroll
      for (int i = 0; i < 8; ++i) ob[i] = f2bf(ap[i]);
      *(u16x8*)(Y + (size_t)row * COUT + c8) = ob;
    }
  }
}

// ---------------- dense gather-GEMM sparse conv (conv1 / conv2) ----------------
template <int CIN, int COUT, int WM, int WN, bool FINAL, int MINB>
__global__ __launch_bounds__(256, MINB) void spconv(
    const unsigned short* __restrict__ X, const unsigned short* __restrict__ Bp,
    const int* __restrict__ nbr, unsigned short* __restrict__ Y,
    float* __restrict__ OUT, const float* __restrict__ DS, int nr) {
  constexpr int BM = 128;
  constexpr int KS = CIN / 32;
  constexpr int WROWS = BM / WM;
  constexpr int WCOLS = COUT / WN;
  constexpr int MF = WROWS / 16;
  constexpr int NF = WCOLS / 16;
  constexpr int CPR = CIN / 8;
  constexpr int SWZ = (CPR < 8 ? CPR - 1 : 7);
  constexpr int ROWB = CIN * 2;
  constexpr int ACH = BM * CPR;
  constexpr int APF = ACH / 256;
  constexpr int NB = KS * NF;

  __shared__ unsigned short As[2][BM * CIN];
  __shared__ int IdxS[27 * BM];

  const int tid = threadIdx.x;
  const int lane = tid & 63;
  const int wave = tid >> 6;
  const int wm = wave / WN;
  const int wn = wave % WN;
  const int base = blockIdx.x * BM;
  const int q = lane >> 4;
  const int l16 = lane & 15;

  for (int f = tid; f < 27 * BM; f += 256) {
    int nn = base + (f & (BM - 1));
    IdxS[f] = (nn < nr) ? nbr[(size_t)(f >> 7) * nr + nn] : nr;
  }
  __syncthreads();

  const unsigned short* bbase = Bp + ((size_t)q * COUT + wn * WCOLS + l16) * 8;

  bf16x8 bA[NB], bB[NB];

  auto loadB = [&](bf16x8(&dst)[NB], int k) {
#pragma unroll
    for (int ks = 0; ks < KS; ++ks)
#pragma unroll
      for (int j = 0; j < NF; ++j)
        dst[ks * NF + j] = *(const bf16x8*)(
            bbase + ((size_t)k * CIN * COUT) + ((size_t)(ks * 4) * COUT + j * 16) * 8);
  };

  auto issueA = [&](int k) {
    const int kb = k & 1;
#pragma unroll
    for (int pp = 0; pp < APF; ++pp) {
      int slot = pp * 256 + tid;
      int r = slot / CPR;
      int cc = (slot % CPR) * 16;
      int c = (cc ^ ((r & SWZ) << 4)) >> 4;
      int g = IdxS[k * BM + r];
      gload16(X + (size_t)g * CIN + c * 8, (char*)(&As[kb][0]) + slot * 16);
    }
  };

  f32x4 acc[MF][NF] = {};

  auto mfmaStep = [&](int kb, const bf16x8(&bf)[NB]) {
    const char* Ab = (const char*)(&As[kb][0]);
#pragma unroll
    for (int ks = 0; ks < KS; ++ks) {
      bf16x8 af[MF];
#pragma unroll
      for (int i = 0; i < MF; ++i) {
        int r = wm * WROWS + i * 16 + l16;
        int db = r * ROWB + (((ks * 64 + q * 16) & (ROWB - 1)) ^ ((r & SWZ) << 4));
        af[i] = __builtin_bit_cast(bf16x8, *(const uint4*)(Ab + db));
      }
#pragma unroll
      for (int i = 0; i < MF; ++i)
#pragma unroll
        for (int j = 0; j < NF; ++j)
          acc[i][j] = __builtin_amdgcn_mfma_f32_16x16x32_bf16(af[i], bf[ks * NF + j],
                                                              acc[i][j], 0, 0, 0);
    }
  };

  loadB(bA, 0);
  issueA(0);

#pragma unroll 1
  for (int k = 0; k < 26; k += 2) {
    loadB(bB, k + 1);
    issueA(k + 1);
    waitvm<NB + APF>();
    BARRIER();
    mfmaStep(0, bA);
    BARRIER();
    if (k + 2 < 27) {
      loadB(bA, k + 2);
      issueA(k + 2);
      waitvm<NB + APF>();
    } else {
      waitvm<0>();
    }
    BARRIER();
    mfmaStep(1, bB);
    BARRIER();
  }
  waitvm<0>();
  BARRIER();
  mfmaStep(0, bA);

#pragma unroll
  for (int i = 0; i < MF; ++i)
#pragma unroll
    for (int j = 0; j < NF; ++j)
#pragma unroll
      for (int r = 0; r < 4; ++r) {
        int row = base + wm * WROWS + i * 16 + q * 4 + r;
        int col = wn * WCOLS + j * 16 + l16;
        if (row < nr) {
          float v = acc[i][j][r];
          if constexpr (FINAL)
            OUT[(size_t)row * COUT + col] = v + DS[(size_t)row * COUT + col];
          else
            Y[(size_t)row * COUT + col] = f2bf(v);
        }
      }
}

// ---------------- launch ----------------
extern "C" void kernel_launch(void* const* d_in, const int* in_sizes, int n_in,
                              void* d_out, int out_size, void* d_ws, size_t ws_size,
                              hipStream_t stream) {
  const float* feats = (const float*)d_in[0];
  const float* W0 = (const float*)d_in[1];
  const float* W1 = (const float*)d_in[2];
  const float* W2 = (const float*)d_in[3];
  const int* nbr = (const int*)d_in[4];
  const int n = in_sizes[0] / 128;
  float* out = (float*)d_out;

  char* p = (char*)d_ws;
  auto take = [&](size_t bytes) {
    char* r = p;
    p += (bytes + 255) & ~(size_t)255;
    return r;
  };
  unsigned short* resB = (unsigned short*)take((size_t)(n + 1) * 128 * 2);
  unsigned short* y0 = (unsigned short*)take((size_t)(n + 1) * 128 * 2);
  unsigned short* y1 = (unsigned short*)take((size_t)(n + 1) * 32 * 2);
  float* ds = (float*)take((size_t)n * 32 * 4);
  unsigned short* p0 = (unsigned short*)take((size_t)27 * 128 * 128 * 2);
  unsigned short* p1 = (unsigned short*)take((size_t)27 * 128 * 32 * 2);
  unsigned short* p2 = (unsigned short*)take((size_t)27 * 32 * 32 * 2);

  prep_kernel<<<(n + 15) / 16, 256, 0, stream>>>(feats, resB, ds, n);
  pack_kernel<<<284, 256, 0, stream>>>(W0, W1, W2, p0, p1, p2);
  zero_tail<<<1, 128, 0, stream>>>(resB + (size_t)n * 128, y0 + (size_t)n * 128,
                                   y1 + (size_t)n * 32);
  // conv0: 128->128, sparse v2 (flat prebuilt tile stream, deep prefetch)
  const int gb0 = (n + 191) / 192;
  spconv_sp<<<gb0, 512, 0, stream>>>(resB, p0, nbr, y0, n);
  const int gb = (n + 127) / 128;
  // conv1: 128->32 dense path. WM=4,WN=1 -> NF=2, NB=8.
  spconv<128, 32, 4, 1, false, 2>
      <<<gb, 256, 0, stream>>>(y0, p1, nbr, y1, nullptr, nullptr, n);
  // conv2: 32->32 dense path. KS=1, NB=2, small LDS -> 4+ blocks/CU.
  spconv<32, 32, 4, 1, true, 4>
      <<<gb, 256, 0, stream>>>(y1, p2, nbr, nullptr, out, ds, n);
}